// Round 2
// baseline (88.087 us; speedup 1.0000x reference)
//
#include <hip/hip_runtime.h>
#include <hip/hip_bf16.h>

// Dynamic conv2d: B=16, C_in=64, H=W=128, C_out=64, K=5 kernels, ks=3, pad=1.
// Strategy: aggregate weights (bf16), transpose x -> [b][h][w][ci] bf16,
// then implicit-GEMM conv with v_mfma_f32_32x32x16_bf16.

typedef __attribute__((ext_vector_type(8))) __bf16 bf16x8;
typedef __attribute__((ext_vector_type(16))) float f32x16;
typedef __attribute__((ext_vector_type(4))) float f32x4;
typedef __attribute__((ext_vector_type(4))) unsigned int u32x4;

#define NB 16
#define CI 64
#define CO 64
#define HH 128
#define WW 128
#define KBANK 5
#define KDIM 576            // CI * 9, k = tap*64 + ci

__device__ __forceinline__ short f2bf(float f) {
    __hip_bfloat16 h = __float2bfloat16(f);
    short s;
    __builtin_memcpy(&s, &h, 2);
    return s;
}

// ---------------- kernel 1: aggregate weights + bias ----------------
// aggw[(b*64+co)*576 + tap*64 + ci] = bf16( sum_k weights[b,k]*Wbank[k,co,ci,tap] )
__global__ void prep_kernel(const float* __restrict__ weights,
                            const float* __restrict__ Wbank,
                            const float* __restrict__ bbank,
                            short* __restrict__ aggw,
                            float* __restrict__ aggb) {
    int idx = blockIdx.x * 256 + threadIdx.x;          // < 16*64*576 = 589824
    int b  = idx / (CO * KDIM);
    int r  = idx - b * (CO * KDIM);
    int co = r / KDIM;
    int k  = r - co * KDIM;
    int tap = k >> 6;          // 0..8
    int ci  = k & 63;
    float s = 0.f;
#pragma unroll
    for (int kk = 0; kk < KBANK; ++kk)
        s += weights[b * KBANK + kk] * Wbank[((kk * CO + co) * CI + ci) * 9 + tap];
    aggw[idx] = f2bf(s);
    if (k == 0) {
        float sb = 0.f;
#pragma unroll
        for (int kk = 0; kk < KBANK; ++kk)
            sb += weights[b * KBANK + kk] * bbank[kk * CO + co];
        aggb[b * CO + co] = sb;
    }
}

// ---------------- kernel 2: x NCHW fp32 -> xT [b][h][w][ci] bf16 ----------------
__global__ void transpose_kernel(const float* __restrict__ x, short* __restrict__ xT) {
    int idx = blockIdx.x * 256 + threadIdx.x;          // < 2^21 chunks of 8 ci
    int c = idx & 7;               // ci chunk
    int w = (idx >> 3) & 127;
    int h = (idx >> 10) & 127;
    int b = idx >> 17;
    union { short s[8]; u32x4 v; } pk;
#pragma unroll
    for (int j = 0; j < 8; ++j) {
        int ci = c * 8 + j;
        pk.s[j] = f2bf(x[((b * CI + ci) * HH + h) * WW + w]);
    }
    *(u32x4*)(xT + (((b * HH + h) * WW + w) * CI + c * 8)) = pk.v;
}

// ---------------- kernel 3: implicit-GEMM conv ----------------
// Block: (hpair, b). 256 threads = 4 waves. Output tile: 64 co x 256 pix (2 rows).
// LDS slab: 4 input rows x 130 pixcols x 64 ci (bf16), 16B-chunk swizzle ch^(pix&7).
// Staging discipline (global_load_lds is wave-uniform base + lane*16):
//   pass 1: ALL lanes load (clamped halo addresses)  -> wave fully active
//   barrier (drains vmcnt)
//   pass 2: overwrite halo chunks with zeros via plain LDS stores
//   barrier
__global__ __launch_bounds__(256) void conv_kernel(const short* __restrict__ xT,
                                                   const short* __restrict__ aggw,
                                                   const float* __restrict__ aggb,
                                                   float* __restrict__ out) {
    __shared__ short slab[4 * 130 * 64];               // 66,560 B

    const int t  = threadIdx.x;
    const int hp = blockIdx.x;                         // 0..63
    const int b  = blockIdx.y;                         // 0..15
    const int h0 = hp * 2;

    // ---- pass 1: stage all 4160 chunks with clamped addresses ----
#pragma unroll
    for (int i = 0; i < 17; ++i) {
        int cid = i * 256 + t;
        if (cid < 4160) {                      // 4160 % 64 == 0 -> wave-uniform
            int row = cid / 1040;
            int rem = cid - row * 1040;
            int pixcol = rem >> 3;
            int ch = rem & 7;
            int hr = h0 + row - 1;
            int w = pixcol - 1;
            int hc = hr < 0 ? 0 : (hr > 127 ? 127 : hr);
            int wc = w  < 0 ? 0 : (w  > 127 ? 127 : w);
            const short* src = xT + (((b * HH + hc) * WW + wc) * CI + ((ch ^ (pixcol & 7)) * 8));
            __builtin_amdgcn_global_load_lds(
                (const __attribute__((address_space(1))) void*)src,
                (__attribute__((address_space(3))) void*)&slab[cid * 8],
                16, 0, 0);
        }
    }
    __syncthreads();                           // drains vmcnt before barrier

    // ---- pass 2: zero the halo chunks ----
#pragma unroll
    for (int i = 0; i < 17; ++i) {
        int cid = i * 256 + t;
        if (cid < 4160) {
            int row = cid / 1040;
            int rem = cid - row * 1040;
            int pixcol = rem >> 3;
            int hr = h0 + row - 1;
            int w = pixcol - 1;
            if ((unsigned)hr >= 128u || (unsigned)w >= 128u)
                *(f32x4*)&slab[cid * 8] = f32x4{0.f, 0.f, 0.f, 0.f};
        }
    }
    __syncthreads();

    const int l  = t & 63;
    const int wv = t >> 6;                 // 0..3
    const int lm = l & 31;                 // m/n lane index
    const int g  = l >> 5;                 // k lane-group
    const int row_local = wv >> 1;         // 0..1 (output row within pair)
    const int wbase = (wv & 1) * 64;       // 0 or 64

    f32x16 acc[2][2];
#pragma unroll
    for (int m = 0; m < 2; ++m)
#pragma unroll
        for (int n = 0; n < 2; ++n)
            acc[m][n] = (f32x16)0.0f;

    const short* aggw_b = aggw + (b * CO) * KDIM;

#pragma unroll
    for (int tap = 0; tap < 9; ++tap) {
        const int dy = tap / 3;
        const int dx = tap - dy * 3;
        // A fragments for this tap: co = m*32+lm, k = tap*64 + q*16 + g*8 + j
        bf16x8 a[2][4];
#pragma unroll
        for (int m = 0; m < 2; ++m)
#pragma unroll
            for (int q = 0; q < 4; ++q)
                a[m][q] = *(const bf16x8*)(aggw_b + (m * 32 + lm) * KDIM + tap * 64 + q * 16 + g * 8);

        const int srow = row_local + dy;   // 0..3
#pragma unroll
        for (int q = 0; q < 4; ++q) {
            bf16x8 bb[2];
#pragma unroll
            for (int n = 0; n < 2; ++n) {
                int pix = wbase + n * 32 + lm + dx;    // pixcol in slab, 0..129
                int chl = q * 2 + g;                   // logical ci chunk
                int slot = chl ^ (pix & 7);
                bb[n] = *(const bf16x8*)&slab[((srow * 130 + pix) * 8 + slot) * 8];
            }
#pragma unroll
            for (int m = 0; m < 2; ++m)
#pragma unroll
                for (int n = 0; n < 2; ++n)
                    acc[m][n] = __builtin_amdgcn_mfma_f32_32x32x16_bf16(a[m][q], bb[n], acc[m][n], 0, 0, 0);
        }
    }

    // ---- epilogue: D[row][col]: col = lane&31, row = (rg&3) + 8*(rg>>2) + 4*g ----
    const int hrow = h0 + row_local;
#pragma unroll
    for (int m = 0; m < 2; ++m) {
#pragma unroll
        for (int n = 0; n < 2; ++n) {
            f32x16 v = acc[m][n];
            int wc = wbase + n * 32 + lm;
#pragma unroll
            for (int rg = 0; rg < 16; ++rg) {
                int rowd = (rg & 3) + 8 * (rg >> 2) + 4 * g;
                int co = m * 32 + rowd;
                out[((b * CO + co) * HH + hrow) * WW + wc] = v[rg] + aggb[b * CO + co];
            }
        }
    }
}

extern "C" void kernel_launch(void* const* d_in, const int* in_sizes, int n_in,
                              void* d_out, int out_size, void* d_ws, size_t ws_size,
                              hipStream_t stream) {
    const float* x       = (const float*)d_in[0];
    const float* weights = (const float*)d_in[1];
    const float* Wbank   = (const float*)d_in[2];
    const float* bbank   = (const float*)d_in[3];
    float* out = (float*)d_out;

    short* xT   = (short*)d_ws;                                  // 33,554,432 B
    short* aggw = (short*)((char*)d_ws + 33554432);              //  1,179,648 B
    float* aggb = (float*)((char*)d_ws + 34734080);              //      4,096 B

    prep_kernel<<<dim3((NB * CO * KDIM) / 256), dim3(256), 0, stream>>>(weights, Wbank, bbank, aggw, aggb);
    transpose_kernel<<<dim3((NB * HH * WW * CI / 8) / 256), dim3(256), 0, stream>>>(x, xT);
    conv_kernel<<<dim3(64, NB), dim3(256), 0, stream>>>(xT, aggw, aggb, out);
}